// Round 6
// baseline (26861.716 us; speedup 1.0000x reference)
//
#include <hip/hip_runtime.h>
#include <stdint.h>

#define RES     1024
#define INPD    16
#define OUTD    8
#define BATCH   32
#define SEQ     4096
#define NCMAX   24             // 24 chunks * 8 = 192 slots/row capacity
#define PASSPAD 3              // first 3 passes per bank: exact Latin square
#define GROUP   8              // row-split: blocks per batch element
#define NPAIR   16             // batch pairs
#define NBLK    (NPAIR * GROUP)   // 128 blocks
#define KMAX    3              // per-thread chunk capacity (8 segs: 3*8=24)

#define MAT_BYTES ((size_t)NCMAX * RES * 8 * 4)   // 786432
// pub[parity][bsel][pair][1024]
#define PUBOFF(par, bs, g) ((((size_t)(par) * 2 + (bs)) * NPAIR + (g)) * RES)

// ---------------------------------------------------------------------------
// Pass 1 (r4-proven): padded row length = 96 + sum_b max(cnt_bank-3, 0)
// ---------------------------------------------------------------------------
__global__ __launch_bounds__(32) void esn_count(const float* __restrict__ W,
                                                uint32_t* __restrict__ eff) {
  const int r = blockIdx.x, b = threadIdx.x;
  const float* row = W + (size_t)r * RES;
  int n = 0;
  for (int k = 0; k < 32; ++k) n += (row[b + 32 * k] != 0.0f) ? 1 : 0;
  int t3 = (n > PASSPAD) ? (n - PASSPAD) : 0;
  for (int o = 16; o; o >>= 1) t3 += __shfl_down(t3, o, 32);
  if (b == 0) eff[r] = (uint32_t)(PASSPAD * 32 + t3);
}

// ---------------------------------------------------------------------------
// Pass 2 (r4-proven): sort rows ascending by eff; per-sorted-wave chunk count
// ---------------------------------------------------------------------------
__global__ __launch_bounds__(1024) void esn_sort(const uint32_t* __restrict__ eff,
                                                 uint32_t* __restrict__ perm,
                                                 uint32_t* __restrict__ wnc) {
  __shared__ uint32_t key[RES];
  const int tid = threadIdx.x;
  key[tid] = (eff[tid] << 10) | (uint32_t)tid;
  __syncthreads();
  for (int len = 2; len <= RES; len <<= 1) {
    for (int s = len >> 1; s > 0; s >>= 1) {
      const int j = tid ^ s;
      if (j > tid) {
        const uint32_t a = key[tid], c = key[j];
        const bool up = ((tid & len) == 0);
        if ((a > c) == up) { key[tid] = c; key[j] = a; }
      }
      __syncthreads();
    }
  }
  const uint32_t k = key[tid];
  perm[tid] = k & 1023u;
  if ((tid & 63) == 63) {
    uint32_t c = ((k >> 10) + 7u) >> 3;
    wnc[tid >> 6] = (c < (uint32_t)NCMAX) ? c : (uint32_t)NCMAX;
  }
}

// ---------------------------------------------------------------------------
// Pass 3 (r4-proven): rotated bank-scheduled pack, packed (col<<18)|bf16(val)
// ---------------------------------------------------------------------------
__global__ __launch_bounds__(32) void esn_pack(const float* __restrict__ W,
                                               const uint32_t* __restrict__ perm,
                                               uint32_t* __restrict__ mato) {
  const int p = blockIdx.x;
  const int b = threadIdx.x;
  __shared__ float    vls[32][16];
  __shared__ uint16_t cls[32][16];
  __shared__ int      cnt[32];
  __shared__ uint32_t rr;
  if (b == 0) rr = perm[p];
  __syncthreads();
  const float* row = W + (size_t)rr * RES;

  int n = 0;
  for (int k = 0; k < 32; ++k) {
    const float v = row[b + 32 * k];
    if (v != 0.0f && n < 16) { vls[b][n] = v; cls[b][n] = (uint16_t)(b + 32 * k); ++n; }
  }
  cnt[b] = n;
  const int rot = p & 31;
  for (int e = b; e < NCMAX * 8; e += 32) {
    const uint32_t padcol = (uint32_t)((rot + (e & 31)) & 31);
    mato[(size_t)(e >> 3) * (RES * 8) + (size_t)p * 8 + (e & 7)] = padcol << 18;
  }
  __syncthreads();

  const int myord = (b - rot) & 31;
  for (int k2 = 0; k2 < n; ++k2) {
    int rank;
    if (k2 < PASSPAD) {
      rank = k2 * 32 + myord;
    } else {
      rank = PASSPAD * 32;
      const int kp = k2 - PASSPAD;
      for (int b2 = 0; b2 < 32; ++b2) {
        int cp = cnt[b2] - PASSPAD; cp = (cp > 0) ? cp : 0;
        const int ord = (b2 - rot) & 31;
        const int lim = kp + ((ord < myord) ? 1 : 0);
        rank += (cp < lim) ? cp : lim;
      }
    }
    if (rank < NCMAX * 8) {
      const uint32_t u  = __float_as_uint(vls[b][k2]);
      const uint32_t bf = (u + 0x7FFFu + ((u >> 16) & 1u)) >> 16;   // RNE bf16
      mato[(size_t)(rank >> 3) * (RES * 8) + (size_t)p * 8 + (rank & 7)] =
          ((uint32_t)cls[b][k2] << 18) | bf;
    }
  }
}

__global__ void esn_init(uint32_t* __restrict__ cntA, uint32_t* __restrict__ cntB) {
  if (threadIdx.x < NBLK) { cntA[threadIdx.x] = 0; cntB[threadIdx.x] = 0; }
}

// ---------------------------------------------------------------------------
// Scan: 8 row-split blocks per batch, 2 batches interleaved per block.
// Phases: A-compute | copy-B(k) | B-compute | copy-A(k+1). Spins target
// flags raised a full phase earlier -> latency hidden.
// ---------------------------------------------------------------------------
#define GATHER8(QA, QB)                                                       \
  a0 = fmaf(__uint_as_float((QA).x << 16), hc[(QA).x >> 18], a0);             \
  a1 = fmaf(__uint_as_float((QA).y << 16), hc[(QA).y >> 18], a1);             \
  a2 = fmaf(__uint_as_float((QA).z << 16), hc[(QA).z >> 18], a2);             \
  a3 = fmaf(__uint_as_float((QA).w << 16), hc[(QA).w >> 18], a3);             \
  a0 = fmaf(__uint_as_float((QB).x << 16), hc[(QB).x >> 18], a0);             \
  a1 = fmaf(__uint_as_float((QB).y << 16), hc[(QB).y >> 18], a1);             \
  a2 = fmaf(__uint_as_float((QB).z << 16), hc[(QB).z >> 18], a2);             \
  a3 = fmaf(__uint_as_float((QB).w << 16), hc[(QB).w >> 18], a3);

__global__ __launch_bounds__(1024) void esn_scan(
    const float* __restrict__ x, const float* __restrict__ state,
    const float* __restrict__ Win, const float* __restrict__ Woutw,
    const float* __restrict__ Woutb,
    const uint32_t* __restrict__ mat, const uint32_t* __restrict__ perm,
    const uint32_t* __restrict__ wnc,
    uint32_t* __restrict__ cntA, uint32_t* __restrict__ cntB,
    float* __restrict__ pub, float* __restrict__ out) {
  __shared__ float hbufA[2][RES], hbufB[2][RES];
  __shared__ float psum[8][128];
  __shared__ uint32_t perml[RES];
  __shared__ __align__(16) float xA[2][INPD], xB[2][INPD];

  const int bid  = blockIdx.x;
  const int grp  = bid >> 3;            // batch pair 0..15
  const int role = bid & 7;
  const int gA   = grp * 2, gB = grp * 2 + 1;
  const int tid  = threadIdx.x;
  const int l    = tid & 63;
  const int v    = tid >> 6;            // wave 0..15
  const int sw   = (v & 1) ? (15 - role) : role;   // sorted wave served
  const int seg  = v >> 1;              // chunk stride class 0..7
  const int p    = sw * 64 + l;         // sorted position
  const int row  = (int)perm[p];
  const int wncv = (int)__builtin_amdgcn_readfirstlane(wnc[sw]);
  const int nct  = (wncv - seg + 7) >> 3;          // chunks for this thread

  perml[tid] = perm[tid];

  // input-projection slice: inputs 2*seg, 2*seg+1 of this row
  const float wi0 = Win[(size_t)row * INPD + 2 * seg];
  const float wi1 = Win[(size_t)row * INPD + 2 * seg + 1];

  // output-projection weights (waves 0..7; wave v owns output v; shared A/B)
  float wo[16];
  const float* wor = Woutw + (size_t)v * RES;
#pragma unroll
  for (int j = 0; j < 16; ++j) wo[j] = (v < OUTD) ? wor[l + 64 * j] : 0.0f;
  const float bw = (v < OUTD) ? Woutb[v] : 0.0f;

  // matrix chunks c = seg + 8k resident in VGPRs
  uint4 qa[KMAX], qb[KMAX];
#pragma unroll
  for (int kk = 0; kk < KMAX; ++kk) {
    if (kk < nct) {
      const uint32_t* cp = mat + ((size_t)(seg + 8 * kk) * RES + (size_t)p) * 8;
      qa[kk] = *(const uint4*)cp;
      qb[kk] = *(const uint4*)(cp + 4);
    } else {
      qa[kk] = make_uint4(0, 0, 0, 0);
      qb[kk] = make_uint4(0, 0, 0, 0);
    }
  }

  hbufA[0][tid] = state[(size_t)gA * RES + tid];
  hbufB[0][tid] = state[(size_t)gB * RES + tid];
  float hregA = (tid < 128) ? state[(size_t)gA * RES + row] : 0.0f;
  float hregB = (tid < 128) ? state[(size_t)gB * RES + row] : 0.0f;
  const float* xrA = x + (size_t)gA * SEQ * INPD;
  const float* xrB = x + (size_t)gB * SEQ * INPD;
  if (v == 15 && l < INPD / 4) ((float4*)xA[0])[l] = ((const float4*)xrA)[l];
  if (v == 14 && l < INPD / 4) ((float4*)xB[0])[l] = ((const float4*)xrB)[l];
  __syncthreads();

  // peer-copy assignment: wave v>=2 copies sorted wave cpsw's 64-run
  int cp_pos = 0, cp_row = 0;
  if (v >= 2) {
    const int j  = v - 2;
    int t1 = j + ((j >= role) ? 1 : 0);
    t1 += ((t1 >= 15 - role) ? 1 : 0);
    cp_pos = t1 * 64 + l;
    cp_row = (int)perml[cp_pos];
  }
  float* finals = out + (size_t)BATCH * SEQ * OUTD;

  for (int k = 0; k < SEQ; ++k) {
    const int par = k & 1;

    // ---------------- phase 1: A-compute ----------------
    if (v == 15 && l < INPD / 4 && k + 1 < SEQ)
      ((float4*)xA[par ^ 1])[l] = ((const float4*)(xrA + (size_t)(k + 1) * INPD))[l];
    if (k > 0 && role == ((k - 1) & 7) && v < OUTD) {
      const float* hc = hbufA[par];
      float s = 0.0f;
#pragma unroll
      for (int j = 0; j < 16; ++j) s = fmaf(hc[l + 64 * j], wo[j], s);
#pragma unroll
      for (int d = 1; d < 64; d <<= 1) s += __shfl_xor(s, d);
      if (l == 0) out[((size_t)gA * SEQ + (k - 1)) * OUTD + v] = s + bw;
    }
    {
      const float* hc = hbufA[par];
      float a0 = wi0 * xA[par][2 * seg], a1 = wi1 * xA[par][2 * seg + 1];
      float a2 = 0.0f, a3 = 0.0f;
#pragma unroll
      for (int kk = 0; kk < KMAX; ++kk) {
        if (kk < nct) { GATHER8(qa[kk], qb[kk]) }
      }
      psum[seg][(v & 1) * 64 + l] = (a0 + a1) + (a2 + a3);
    }
    __syncthreads();                                   // B1
    if (tid < 128) {
      float s = 0.0f;
#pragma unroll
      for (int s8 = 0; s8 < 8; ++s8) s += psum[s8][tid];
      const float e  = exp2f(s * 2.885390081777927f);
      const float th = 1.0f - 2.0f * __builtin_amdgcn_rcpf(e + 1.0f);
      const float hn = fmaf(0.7f, th, 0.3f * hregA);
      hregA = hn;
      hbufA[par ^ 1][row] = hn;
      __hip_atomic_store(&pub[PUBOFF(par ^ 1, 0, grp) + p], hn,
                         __ATOMIC_RELAXED, __HIP_MEMORY_SCOPE_AGENT);
    }
    __syncthreads();                                   // B2 (pub drained)
    if (tid == 0)
      __hip_atomic_store(&cntA[bid], (uint32_t)(k + 1), __ATOMIC_RELEASE,
                         __HIP_MEMORY_SCOPE_AGENT);

    // ---------------- phase 2: copy B(k) ----------------
    if (k > 0) {
      if (tid < GROUP && tid != role) {
        const uint32_t want = (uint32_t)k;
        while (__hip_atomic_load(&cntB[grp * GROUP + tid], __ATOMIC_ACQUIRE,
                                 __HIP_MEMORY_SCOPE_AGENT) < want)
          __builtin_amdgcn_s_sleep(1);
      }
      __syncthreads();                                 // B3
      if (v >= 2)
        hbufB[par][cp_row] =
            __hip_atomic_load(&pub[PUBOFF(par, 1, grp) + cp_pos],
                              __ATOMIC_RELAXED, __HIP_MEMORY_SCOPE_AGENT);
    }
    __syncthreads();                                   // B4

    // ---------------- phase 3: B-compute ----------------
    if (v == 14 && l < INPD / 4 && k + 1 < SEQ)
      ((float4*)xB[par ^ 1])[l] = ((const float4*)(xrB + (size_t)(k + 1) * INPD))[l];
    if (k > 0 && role == ((k - 1) & 7) && v < OUTD) {
      const float* hc = hbufB[par];
      float s = 0.0f;
#pragma unroll
      for (int j = 0; j < 16; ++j) s = fmaf(hc[l + 64 * j], wo[j], s);
#pragma unroll
      for (int d = 1; d < 64; d <<= 1) s += __shfl_xor(s, d);
      if (l == 0) out[((size_t)gB * SEQ + (k - 1)) * OUTD + v] = s + bw;
    }
    {
      const float* hc = hbufB[par];
      float a0 = wi0 * xB[par][2 * seg], a1 = wi1 * xB[par][2 * seg + 1];
      float a2 = 0.0f, a3 = 0.0f;
#pragma unroll
      for (int kk = 0; kk < KMAX; ++kk) {
        if (kk < nct) { GATHER8(qa[kk], qb[kk]) }
      }
      psum[seg][(v & 1) * 64 + l] = (a0 + a1) + (a2 + a3);
    }
    __syncthreads();                                   // B5
    if (tid < 128) {
      float s = 0.0f;
#pragma unroll
      for (int s8 = 0; s8 < 8; ++s8) s += psum[s8][tid];
      const float e  = exp2f(s * 2.885390081777927f);
      const float th = 1.0f - 2.0f * __builtin_amdgcn_rcpf(e + 1.0f);
      const float hn = fmaf(0.7f, th, 0.3f * hregB);
      hregB = hn;
      hbufB[par ^ 1][row] = hn;
      __hip_atomic_store(&pub[PUBOFF(par ^ 1, 1, grp) + p], hn,
                         __ATOMIC_RELAXED, __HIP_MEMORY_SCOPE_AGENT);
    }
    __syncthreads();                                   // B6
    if (tid == 0)
      __hip_atomic_store(&cntB[bid], (uint32_t)(k + 1), __ATOMIC_RELEASE,
                         __HIP_MEMORY_SCOPE_AGENT);

    // ---------------- phase 4: copy A(k+1) ----------------
    if (tid < GROUP && tid != role) {
      const uint32_t want = (uint32_t)(k + 1);
      while (__hip_atomic_load(&cntA[grp * GROUP + tid], __ATOMIC_ACQUIRE,
                               __HIP_MEMORY_SCOPE_AGENT) < want)
        __builtin_amdgcn_s_sleep(1);
    }
    __syncthreads();                                   // B7
    if (v >= 2)
      hbufA[par ^ 1][cp_row] =
          __hip_atomic_load(&pub[PUBOFF(par ^ 1, 0, grp) + cp_pos],
                            __ATOMIC_RELAXED, __HIP_MEMORY_SCOPE_AGENT);
    __syncthreads();                                   // B8
  }

  // ---------------- epilogue ----------------
  // complete hB(SEQ) (parity 0)
  if (tid < GROUP && tid != role) {
    while (__hip_atomic_load(&cntB[grp * GROUP + tid], __ATOMIC_ACQUIRE,
                             __HIP_MEMORY_SCOPE_AGENT) < (uint32_t)SEQ)
      __builtin_amdgcn_s_sleep(1);
  }
  __syncthreads();
  if (v >= 2)
    hbufB[0][cp_row] =
        __hip_atomic_load(&pub[PUBOFF(0, 1, grp) + cp_pos],
                          __ATOMIC_RELAXED, __HIP_MEMORY_SCOPE_AGENT);
  __syncthreads();

  if (role == 0) {
    if (v < OUTD) {
      float sA = 0.0f, sB = 0.0f;
#pragma unroll
      for (int j = 0; j < 16; ++j) {
        sA = fmaf(hbufA[0][l + 64 * j], wo[j], sA);
        sB = fmaf(hbufB[0][l + 64 * j], wo[j], sB);
      }
#pragma unroll
      for (int d = 1; d < 64; d <<= 1) {
        sA += __shfl_xor(sA, d);
        sB += __shfl_xor(sB, d);
      }
      if (l == 0) {
        out[((size_t)gA * SEQ + (SEQ - 1)) * OUTD + v] = sA + bw;
        out[((size_t)gB * SEQ + (SEQ - 1)) * OUTD + v] = sB + bw;
      }
    }
    finals[(size_t)gA * RES + tid] = hbufA[0][tid];
    finals[(size_t)gB * RES + tid] = hbufB[0][tid];
  }
}

// ---------------------------------------------------------------------------
extern "C" void kernel_launch(void* const* d_in, const int* in_sizes, int n_in,
                              void* d_out, int out_size, void* d_ws, size_t ws_size,
                              hipStream_t stream) {
  const float* x     = (const float*)d_in[0];
  const float* state = (const float*)d_in[1];
  const float* Win   = (const float*)d_in[2];
  const float* Wres  = (const float*)d_in[3];
  const float* Woutw = (const float*)d_in[4];
  const float* Woutb = (const float*)d_in[5];
  float* out = (float*)d_out;

  uint8_t*  ws   = (uint8_t*)d_ws;
  uint32_t* mat  = (uint32_t*)ws;
  uint32_t* eff  = (uint32_t*)(ws + MAT_BYTES);
  uint32_t* perm = (uint32_t*)(ws + MAT_BYTES + 4096);
  uint32_t* wnc  = (uint32_t*)(ws + MAT_BYTES + 8192);
  uint32_t* cntA = (uint32_t*)(ws + MAT_BYTES + 12288);
  uint32_t* cntB = (uint32_t*)(ws + MAT_BYTES + 14336);
  float*    pub  = (float*)(ws + MAT_BYTES + 16384);

  esn_count<<<RES, 32, 0, stream>>>(Wres, eff);
  esn_sort<<<1, RES, 0, stream>>>(eff, perm, wnc);
  esn_pack<<<RES, 32, 0, stream>>>(Wres, perm, mat);
  esn_init<<<1, 256, 0, stream>>>(cntA, cntB);
  esn_scan<<<NBLK, RES, 0, stream>>>(x, state, Win, Woutw, Woutb,
                                     mat, perm, wnc, cntA, cntB, pub, out);
}

// Round 7
// 25548.398 us; speedup vs baseline: 1.0514x; 1.0514x over previous
//
#include <hip/hip_runtime.h>
#include <stdint.h>

#define RES     1024
#define INPD    16
#define OUTD    8
#define BATCH   32
#define SEQ     4096
#define NCMAX   24             // capacity: 24 chunks * 8 = 192 ranks/row
#define DEPTH   13             // per-(lane,bank) list depth in scheduler
#define OVMAX   6              // overflow slots per lane (bank cnt > DEPTH)

// ws layout:
//   mat:  u32 [NCMAX][1024][8]   packed (col<<18)|bf16(val); pads val=0
//   eff:  u32 [1024]             nz per row
//   perm: u32 [1024]             rows sorted ascending by nz
//   wnc:  u32 [16]               per-wave chunk count (from scheduler)
#define MAT_BYTES ((size_t)NCMAX * RES * 8 * 4)   // 786432

// ---------------------------------------------------------------------------
// Pass 1: nz count per row
// ---------------------------------------------------------------------------
__global__ __launch_bounds__(32) void esn_count(const float* __restrict__ W,
                                                uint32_t* __restrict__ eff) {
  const int r = blockIdx.x, b = threadIdx.x;
  const float* row = W + (size_t)r * RES;
  int n = 0;
  for (int k = 0; k < 32; ++k) n += (row[b + 32 * k] != 0.0f) ? 1 : 0;
  for (int o = 16; o; o >>= 1) n += __shfl_down(n, o, 32);
  if (b == 0) eff[r] = (uint32_t)n;
}

// ---------------------------------------------------------------------------
// Pass 2: bitonic sort rows ascending by nz -> perm
// ---------------------------------------------------------------------------
__global__ __launch_bounds__(1024) void esn_sort(const uint32_t* __restrict__ eff,
                                                 uint32_t* __restrict__ perm) {
  __shared__ uint32_t key[RES];
  const int tid = threadIdx.x;
  key[tid] = (eff[tid] << 10) | (uint32_t)tid;
  __syncthreads();
  for (int len = 2; len <= RES; len <<= 1) {
    for (int s = len >> 1; s > 0; s >>= 1) {
      const int j = tid ^ s;
      if (j > tid) {
        const uint32_t a = key[tid], c = key[j];
        const bool up = ((tid & len) == 0);
        if ((a > c) == up) { key[tid] = c; key[j] = a; }
      }
      __syncthreads();
    }
  }
  perm[tid] = key[tid] & 1023u;
}

// ---------------------------------------------------------------------------
// Pass 3: JOINT per-wave scheduler. One block (64 threads = 1 wave) per
// sorted wave. Rank by rank, each lane emits one nz under a hard <=2
// lanes/bank/rank constraint (LDS atomic claim + undo). Guarantees every
// gather instruction in the scan is bank-conflict-free by construction.
// ---------------------------------------------------------------------------
__global__ __launch_bounds__(64) void esn_sched(const float* __restrict__ W,
                                                const uint32_t* __restrict__ perm,
                                                uint32_t* __restrict__ mato,
                                                uint32_t* __restrict__ wnc) {
  __shared__ uint16_t cols[64][32][DEPTH];   // 53248 B
  __shared__ uint32_t cnt[64][32];           //  8192 B
  __shared__ uint32_t bankctr[32];           //   128 B
  __shared__ uint16_t ovf[64][OVMAX];        //   768 B
  __shared__ uint32_t ovn[64];               //   256 B
  const int wv = blockIdx.x;                 // sorted wave 0..15
  const int l  = threadIdx.x;                // lane = local row
  const int p  = wv * 64 + l;                // sorted position (scan tid)
  const int row = (int)perm[p];

  for (int i = l; i < 64 * 32; i += 64) ((uint32_t*)cnt)[i] = 0;
  ovn[l] = 0;
  __syncthreads();

  // fill: cooperative per row (coalesced loads), bucket by bank = col&31
  for (int r2 = 0; r2 < 64; ++r2) {
    const float* wr = W + (size_t)perm[wv * 64 + r2] * RES;
    for (int k = 0; k < 16; ++k) {
      const int c = k * 64 + l;
      const float v = wr[c];
      if (v != 0.0f) {
        const int b = c & 31;
        const uint32_t d = atomicAdd(&cnt[r2][b], 1u);
        if (d < DEPTH) cols[r2][b][d] = (uint16_t)c;
        else { const uint32_t o = atomicAdd(&ovn[r2], 1u);
               if (o < OVMAX) ovf[r2][o] = (uint16_t)c; }
      }
    }
  }
  __syncthreads();

  int trem = 0;
  for (int b = 0; b < 32; ++b) {
    uint32_t c = cnt[l][b];
    if (c > DEPTH) { cnt[l][b] = DEPTH; c = DEPTH; }
    trem += (int)c;
  }
  int myov = (int)ovn[l]; if (myov > OVMAX) myov = OVMAX;
  trem += myov;

  int wns = NCMAX * 8;
  for (int s = 0; s < NCMAX * 8; ++s) {
    if (l < 32) bankctr[l] = 0;
    __syncthreads();

    int emit = -1;
    if (trem > 0) {
      uint32_t tried = 0;
      for (int it = 0; it < 6 && emit < 0; ++it) {
        int bb = -1; uint32_t bc = 0;
        for (int b = 0; b < 32; ++b) {
          if (tried & (1u << b)) continue;
          const uint32_t c = cnt[l][b];
          if (c > bc) { bc = c; bb = b; }
        }
        if (bb < 0) break;
        const uint32_t old = atomicAdd(&bankctr[bb], 1u);
        if (old < 2u) {
          const uint32_t d = cnt[l][bb] - 1u;
          cnt[l][bb] = d;
          emit = (int)cols[l][bb][d];
          --trem;
        } else { atomicSub(&bankctr[bb], 1u); tried |= 1u << bb; }
      }
      if (emit < 0 && myov > 0) {            // overflow elements (fixed bank)
        const int c = (int)ovf[l][myov - 1];
        const int b = c & 31;
        if (!(tried & (1u << b))) {
          const uint32_t old = atomicAdd(&bankctr[b], 1u);
          if (old < 2u) { emit = c; --myov; --trem; }
          else atomicSub(&bankctr[b], 1u);
        }
      }
    }

    uint32_t word;
    if (emit >= 0) {
      word = ((uint32_t)emit << 18) | 0x10000u;          // bit16 = real
    } else {                                             // pad: claim a free bank
      int pb = -1;
      for (int i = 0; i < 32; ++i) {
        const int b = (l + s + i) & 31;
        const uint32_t old = atomicAdd(&bankctr[b], 1u);
        if (old < 2u) { pb = b; break; }
        atomicSub(&bankctr[b], 1u);
      }
      if (pb < 0) pb = l & 31;
      word = (uint32_t)pb << 18;                          // val bits = 0
    }
    mato[(size_t)(s >> 3) * (RES * 8) + (size_t)p * 8 + (s & 7)] = word;

    if (__ballot(trem > 0) == 0ull) { wns = s + 1; break; }
    __syncthreads();
  }

  // pad remaining ranks up to the chunk boundary (perfect 2/bank pattern)
  const int wfin = (wns + 7) & ~7;
  for (int s = wns; s < wfin; ++s)
    mato[(size_t)(s >> 3) * (RES * 8) + (size_t)p * 8 + (s & 7)] =
        ((uint32_t)((l + s) & 31)) << 18;
  if (l == 0) wnc[wv] = (uint32_t)(wfin >> 3);

  // pass 2: fill bf16 values for real slots (same-thread RAW, ordered)
  const float* wr = W + (size_t)row * RES;
  for (int s = 0; s < wns; ++s) {
    const size_t off = (size_t)(s >> 3) * (RES * 8) + (size_t)p * 8 + (s & 7);
    const uint32_t u = mato[off];
    if (u & 0x10000u) {
      const uint32_t fu = __float_as_uint(wr[u >> 18]);
      const uint32_t bf = (fu + 0x7FFFu + ((fu >> 16) & 1u)) >> 16;  // RNE bf16
      mato[off] = (u & 0xFFFC0000u) | bf;
    }
  }
}

// ---------------------------------------------------------------------------
// Scan (r4-proven, verbatim): one block per batch, packed-dword stream with
// depth-1 prefetch, conflict-free LDS gathers, 8 projection waves, 1 barrier.
// ---------------------------------------------------------------------------
#define GATHER8(QA, QB)                                                       \
  a0 = fmaf(__uint_as_float((QA).x << 16), hc[(QA).x >> 18], a0);             \
  a1 = fmaf(__uint_as_float((QA).y << 16), hc[(QA).y >> 18], a1);             \
  a2 = fmaf(__uint_as_float((QA).z << 16), hc[(QA).z >> 18], a2);             \
  a3 = fmaf(__uint_as_float((QA).w << 16), hc[(QA).w >> 18], a3);             \
  a0 = fmaf(__uint_as_float((QB).x << 16), hc[(QB).x >> 18], a0);             \
  a1 = fmaf(__uint_as_float((QB).y << 16), hc[(QB).y >> 18], a1);             \
  a2 = fmaf(__uint_as_float((QB).z << 16), hc[(QB).z >> 18], a2);             \
  a3 = fmaf(__uint_as_float((QB).w << 16), hc[(QB).w >> 18], a3);

__global__ __launch_bounds__(1024) void esn_scan(
    const float* __restrict__ x, const float* __restrict__ state,
    const float* __restrict__ Win, const float* __restrict__ Woutw,
    const float* __restrict__ Woutb,
    const uint32_t* __restrict__ mat, const uint32_t* __restrict__ perm,
    const uint32_t* __restrict__ wnc,
    float* __restrict__ out) {
  __shared__ float  hbuf[2][RES];
  __shared__ float4 xbuf[2][INPD / 4];

  const int b    = blockIdx.x;
  const int tid  = threadIdx.x;
  const int wave = tid >> 6;
  const int lane = tid & 63;
  const int row  = (int)perm[tid];
  const int ncw  = (int)__builtin_amdgcn_readfirstlane(wnc[wave]);

  const float4* winp = (const float4*)(Win + (size_t)row * INPD);
  const float4 w0 = winp[0], w1 = winp[1], w2 = winp[2], w3 = winp[3];

  float wo[16];
  const float* wor = Woutw + (size_t)wave * RES;
#pragma unroll
  for (int j = 0; j < 16; ++j) wo[j] = (wave < OUTD) ? wor[lane + 64 * j] : 0.0f;
  const float bw = (wave < OUTD) ? Woutb[wave] : 0.0f;

  float hreg = state[(size_t)b * RES + row];
  hbuf[0][row] = hreg;
  const float* xr = x + (size_t)b * SEQ * INPD;
  if (tid < INPD / 4) xbuf[0][tid] = ((const float4*)xr)[tid];
  __syncthreads();

  const uint32_t* mp = mat + (size_t)tid * 8;
  float* finals = out + (size_t)BATCH * SEQ * OUTD;

  for (int t = 0; t < SEQ; ++t) {
    const int par = t & 1;
    const float* hc = hbuf[par];

    if (t > 0 && wave < OUTD) {
      float s = 0.0f;
#pragma unroll
      for (int j = 0; j < 16; ++j) s = fmaf(hc[lane + 64 * j], wo[j], s);
#pragma unroll
      for (int d = 1; d < 64; d <<= 1) s += __shfl_xor(s, d);
      if (lane == 0) out[((size_t)b * SEQ + (t - 1)) * OUTD + wave] = s + bw;
    }
    if (tid < INPD / 4 && t + 1 < SEQ)
      xbuf[par ^ 1][tid] = ((const float4*)(xr + (size_t)(t + 1) * INPD))[tid];

    const float4 xa = xbuf[par][0], xbv = xbuf[par][1];
    const float4 xc = xbuf[par][2], xd  = xbuf[par][3];
    float a0 = 0.f, a1 = 0.f, a2 = 0.f, a3 = 0.f;
    a0 = fmaf(xa.x, w0.x, a0);  a1 = fmaf(xa.y, w0.y, a1);
    a2 = fmaf(xa.z, w0.z, a2);  a3 = fmaf(xa.w, w0.w, a3);
    a0 = fmaf(xbv.x, w1.x, a0); a1 = fmaf(xbv.y, w1.y, a1);
    a2 = fmaf(xbv.z, w1.z, a2); a3 = fmaf(xbv.w, w1.w, a3);
    a0 = fmaf(xc.x, w2.x, a0);  a1 = fmaf(xc.y, w2.y, a1);
    a2 = fmaf(xc.z, w2.z, a2);  a3 = fmaf(xc.w, w2.w, a3);
    a0 = fmaf(xd.x, w3.x, a0);  a1 = fmaf(xd.y, w3.y, a1);
    a2 = fmaf(xd.z, w3.z, a2);  a3 = fmaf(xd.w, w3.w, a3);

    uint4 qa = *(const uint4*)mp;
    uint4 qb = *(const uint4*)(mp + 4);
    for (int c = 0; c < ncw - 1; ++c) {
      const uint32_t* cpn = mp + (size_t)(c + 1) * (RES * 8);
      const uint4 na = *(const uint4*)cpn;
      const uint4 nb = *(const uint4*)(cpn + 4);
      GATHER8(qa, qb)
      qa = na; qb = nb;
    }
    GATHER8(qa, qb)

    const float acc = (a0 + a1) + (a2 + a3);
    const float e   = exp2f(acc * 2.885390081777927f);
    const float th  = 1.0f - 2.0f * __builtin_amdgcn_rcpf(e + 1.0f);
    const float hn  = fmaf(0.7f, th, 0.3f * hreg);
    hreg = hn;
    hbuf[par ^ 1][row] = hn;
    __syncthreads();
  }

  if (wave < OUTD) {
    float s = 0.0f;
#pragma unroll
    for (int j = 0; j < 16; ++j) s = fmaf(hbuf[0][lane + 64 * j], wo[j], s);
#pragma unroll
    for (int d = 1; d < 64; d <<= 1) s += __shfl_xor(s, d);
    if (lane == 0) out[((size_t)b * SEQ + (SEQ - 1)) * OUTD + wave] = s + bw;
  }
  finals[(size_t)b * RES + row] = hreg;
}

// ---------------------------------------------------------------------------
extern "C" void kernel_launch(void* const* d_in, const int* in_sizes, int n_in,
                              void* d_out, int out_size, void* d_ws, size_t ws_size,
                              hipStream_t stream) {
  const float* x     = (const float*)d_in[0];
  const float* state = (const float*)d_in[1];
  const float* Win   = (const float*)d_in[2];
  const float* Wres  = (const float*)d_in[3];
  const float* Woutw = (const float*)d_in[4];
  const float* Woutb = (const float*)d_in[5];
  float* out = (float*)d_out;

  uint8_t*  ws   = (uint8_t*)d_ws;
  uint32_t* mat  = (uint32_t*)ws;
  uint32_t* eff  = (uint32_t*)(ws + MAT_BYTES);
  uint32_t* perm = (uint32_t*)(ws + MAT_BYTES + 4096);
  uint32_t* wnc  = (uint32_t*)(ws + MAT_BYTES + 8192);

  esn_count<<<RES, 32, 0, stream>>>(Wres, eff);
  esn_sort<<<1, RES, 0, stream>>>(eff, perm);
  esn_sched<<<16, 64, 0, stream>>>(Wres, perm, mat, wnc);
  esn_scan<<<BATCH, RES, 0, stream>>>(x, state, Win, Woutw, Woutb,
                                      mat, perm, wnc, out);
}

// Round 8
// 24214.890 us; speedup vs baseline: 1.1093x; 1.0551x over previous
//
#include <hip/hip_runtime.h>
#include <stdint.h>

#define RES     1024
#define INPD    16
#define OUTD    8
#define BATCH   32
#define SEQ     4096
#define NCMAX   24             // capacity: 24 chunks * 8 = 192 ranks/row
#define DEPTH   14             // per-(lane,bank) bucket depth in scheduler
#define OVMAX   8              // overflow slots per lane

// ws layout:
//   mat:  u32 [NCMAX][1024][8]  packed (byteofs<<16)|bf16(val); pads val=0
//   eff:  u32 [1024]            nz per row
//   perm: u32 [1024]            rows sorted ascending by nz
//   wnc:  u32 [16]              per-wave chunk count
//   invp: u32 [1024]            invp[row] = sorted position
#define MAT_BYTES ((size_t)NCMAX * RES * 8 * 4)   // 786432

// ---------------------------------------------------------------------------
// Pass 1: nz count per row
// ---------------------------------------------------------------------------
__global__ __launch_bounds__(32) void esn_count(const float* __restrict__ W,
                                                uint32_t* __restrict__ eff) {
  const int r = blockIdx.x, b = threadIdx.x;
  const float* row = W + (size_t)r * RES;
  int n = 0;
  for (int k = 0; k < 32; ++k) n += (row[b + 32 * k] != 0.0f) ? 1 : 0;
  for (int o = 16; o; o >>= 1) n += __shfl_down(n, o, 32);
  if (b == 0) eff[r] = (uint32_t)n;
}

// ---------------------------------------------------------------------------
// Pass 2: bitonic sort rows ascending by nz -> perm, invp
// ---------------------------------------------------------------------------
__global__ __launch_bounds__(1024) void esn_sort(const uint32_t* __restrict__ eff,
                                                 uint32_t* __restrict__ perm,
                                                 uint32_t* __restrict__ invp) {
  __shared__ uint32_t key[RES];
  const int tid = threadIdx.x;
  key[tid] = (eff[tid] << 10) | (uint32_t)tid;
  __syncthreads();
  for (int len = 2; len <= RES; len <<= 1) {
    for (int s = len >> 1; s > 0; s >>= 1) {
      const int j = tid ^ s;
      if (j > tid) {
        const uint32_t a = key[tid], c = key[j];
        const bool up = ((tid & len) == 0);
        if ((a > c) == up) { key[tid] = c; key[j] = a; }
      }
      __syncthreads();
    }
  }
  const uint32_t r = key[tid] & 1023u;
  perm[tid] = r;
  invp[r] = (uint32_t)tid;
}

// ---------------------------------------------------------------------------
// Pass 3: HALF-AWARE joint scheduler. One wave per sorted 64-row group.
// Rank by rank, each lane emits one nz under <=1 lane/bank per 32-lane HALF
// (the true gfx950 free condition). Bank of col c = invp[c]&31 (sorted-space
// h storage). Force-emit near capacity guarantees completeness.
// ---------------------------------------------------------------------------
__global__ __launch_bounds__(64) void esn_sched(const float* __restrict__ W,
                                                const uint32_t* __restrict__ perm,
                                                const uint32_t* __restrict__ invp,
                                                uint32_t* __restrict__ mato,
                                                uint32_t* __restrict__ wnc) {
  __shared__ uint16_t cols[64][32][DEPTH];
  __shared__ uint32_t cnt[64][32];
  __shared__ uint32_t bankctr[64];          // [half][bank]
  __shared__ uint16_t ovf[64][OVMAX];
  __shared__ uint32_t ovn[64];
  __shared__ uint16_t invl[RES];
  const int wv = blockIdx.x;                // sorted wave 0..15
  const int l  = threadIdx.x;
  const int p  = wv * 64 + l;
  const int row = (int)perm[p];
  const int half = l >> 5;

  for (int i = l; i < 64 * 32; i += 64) ((uint32_t*)cnt)[i] = 0;
  ovn[l] = 0;
  for (int i = l; i < RES; i += 64) invl[i] = (uint16_t)invp[i];
  __syncthreads();

  // bucket fill: cooperative per row, bucket by bank = invp[col]&31
  for (int r2 = 0; r2 < 64; ++r2) {
    const float* wr2 = W + (size_t)perm[wv * 64 + r2] * RES;
    for (int k = 0; k < 16; ++k) {
      const int c = k * 64 + l;
      if (wr2[c] != 0.0f) {
        const int b = (int)(invl[c] & 31u);
        const uint32_t d = atomicAdd(&cnt[r2][b], 1u);
        if (d < DEPTH) cols[r2][b][d] = (uint16_t)c;
        else { const uint32_t o = atomicAdd(&ovn[r2], 1u);
               if (o < OVMAX) ovf[r2][o] = (uint16_t)c; }
      }
    }
  }
  __syncthreads();

  int trem = 0;
  for (int b = 0; b < 32; ++b) {
    uint32_t c = cnt[l][b];
    if (c > DEPTH) { cnt[l][b] = DEPTH; c = DEPTH; }
    trem += (int)c;
  }
  int myov = (int)ovn[l]; if (myov > OVMAX) myov = OVMAX;
  trem += myov;

  const float* wr = W + (size_t)row * RES;
  int wns = NCMAX * 8;
  for (int s = 0; s < NCMAX * 8; ++s) {
    bankctr[l] = 0;
    __syncthreads();

    int emitc = -1;
    if (trem > 0) {
      uint32_t tried = 0;
      for (int it = 0; it < 12 && emitc < 0; ++it) {
        int bb = -1; uint32_t bc = 0;
        for (int b = 0; b < 32; ++b) {
          if (tried & (1u << b)) continue;
          const uint32_t c = cnt[l][b];
          if (c > bc) { bc = c; bb = b; }
        }
        if (bb < 0) break;
        if (atomicAdd(&bankctr[half * 32 + bb], 1u) == 0u) {
          const uint32_t d = cnt[l][bb] - 1u;
          cnt[l][bb] = d;
          emitc = (int)cols[l][bb][d];
          --trem;
        } else { atomicSub(&bankctr[half * 32 + bb], 1u); tried |= 1u << bb; }
      }
      if (emitc < 0 && myov > 0) {
        const int c = (int)ovf[l][myov - 1];
        const int b = (int)(invl[c] & 31u);
        if (!(tried & (1u << b))) {
          if (atomicAdd(&bankctr[half * 32 + b], 1u) == 0u) { emitc = c; --myov; --trem; }
          else atomicSub(&bankctr[half * 32 + b], 1u);
        }
      }
      if (emitc < 0 && s >= NCMAX * 8 - 16) {   // force: completeness > banks
        for (int b = 0; b < 32 && emitc < 0; ++b) {
          const uint32_t c = cnt[l][b];
          if (c) { cnt[l][b] = c - 1u; emitc = (int)cols[l][b][c - 1u]; --trem; }
        }
        if (emitc < 0 && myov > 0) { emitc = (int)ovf[l][myov - 1]; --myov; --trem; }
      }
    }

    uint32_t word;
    if (emitc >= 0) {
      const uint32_t fu = __float_as_uint(wr[emitc]);
      const uint32_t bf = (fu + 0x7FFFu + ((fu >> 16) & 1u)) >> 16;  // RNE bf16
      word = (((uint32_t)invl[emitc] * 4u) << 16) | bf;
    } else {                                   // pad: claim any free bank
      int pb = -1;
      for (int i = 0; i < 32; ++i) {
        const int b = (l + s + i) & 31;
        if (atomicAdd(&bankctr[half * 32 + b], 1u) == 0u) { pb = b; break; }
        atomicSub(&bankctr[half * 32 + b], 1u);
      }
      if (pb < 0) pb = l & 31;
      word = ((uint32_t)pb * 4u) << 16;        // val bits = 0
    }
    mato[(size_t)(s >> 3) * (RES * 8) + (size_t)p * 8 + (s & 7)] = word;

    if (__ballot(trem > 0) == 0ull) { wns = s + 1; break; }
    __syncthreads();
  }

  const int wfin = (wns + 7) & ~7;             // tail pads: (l+s)&31 rotation
  for (int s = wns; s < wfin; ++s)
    mato[(size_t)(s >> 3) * (RES * 8) + (size_t)p * 8 + (s & 7)] =
        ((uint32_t)(((l + s) & 31) * 4u)) << 16;
  if (l == 0) wnc[wv] = (uint32_t)(wfin >> 3);
}

// ---------------------------------------------------------------------------
// Scan: one block per batch. h in SORTED space (linear writes), double-buffer
// at LDS offset 0/4096 with compile-time parity; 3-op gather unpack.
// ---------------------------------------------------------------------------
#define G8(QA, QB, PB)                                                        \
  a0 = fmaf(__uint_as_float((QA).x << 16),                                    \
            *(const float*)((const char*)smem + (PB) + ((QA).x >> 16)), a0);  \
  a1 = fmaf(__uint_as_float((QA).y << 16),                                    \
            *(const float*)((const char*)smem + (PB) + ((QA).y >> 16)), a1);  \
  a2 = fmaf(__uint_as_float((QA).z << 16),                                    \
            *(const float*)((const char*)smem + (PB) + ((QA).z >> 16)), a2);  \
  a3 = fmaf(__uint_as_float((QA).w << 16),                                    \
            *(const float*)((const char*)smem + (PB) + ((QA).w >> 16)), a3);  \
  a0 = fmaf(__uint_as_float((QB).x << 16),                                    \
            *(const float*)((const char*)smem + (PB) + ((QB).x >> 16)), a0);  \
  a1 = fmaf(__uint_as_float((QB).y << 16),                                    \
            *(const float*)((const char*)smem + (PB) + ((QB).y >> 16)), a1);  \
  a2 = fmaf(__uint_as_float((QB).z << 16),                                    \
            *(const float*)((const char*)smem + (PB) + ((QB).z >> 16)), a2);  \
  a3 = fmaf(__uint_as_float((QB).w << 16),                                    \
            *(const float*)((const char*)smem + (PB) + ((QB).w >> 16)), a3);

#define STEP(PAR, T)                                                          \
  {                                                                           \
    if ((T) > 0 && wave < OUTD) {                                             \
      float s = 0.0f;                                                         \
      _Pragma("unroll")                                                       \
      for (int j = 0; j < 16; ++j)                                            \
        s = fmaf(smem[(PAR) * RES + lane + 64 * j], wo[j], s);                \
      _Pragma("unroll")                                                       \
      for (int d = 1; d < 64; d <<= 1) s += __shfl_xor(s, d);                 \
      if (lane == 0) out[((size_t)b * SEQ + ((T) - 1)) * OUTD + wave] = s + bw; \
    }                                                                         \
    if (tid < 4 && (T) + 1 < SEQ)                                             \
      ((float4*)(smem + 2 * RES))[((PAR) ^ 1) * 4 + tid] =                    \
          ((const float4*)(xr + (size_t)((T) + 1) * INPD))[tid];              \
    const float4 xa  = ((const float4*)(smem + 2 * RES))[(PAR) * 4 + 0];      \
    const float4 xbv = ((const float4*)(smem + 2 * RES))[(PAR) * 4 + 1];      \
    const float4 xc  = ((const float4*)(smem + 2 * RES))[(PAR) * 4 + 2];      \
    const float4 xd  = ((const float4*)(smem + 2 * RES))[(PAR) * 4 + 3];      \
    float a0 = 0.f, a1 = 0.f, a2 = 0.f, a3 = 0.f;                             \
    a0 = fmaf(xa.x, w0.x, a0);  a1 = fmaf(xa.y, w0.y, a1);                    \
    a2 = fmaf(xa.z, w0.z, a2);  a3 = fmaf(xa.w, w0.w, a3);                    \
    a0 = fmaf(xbv.x, w1.x, a0); a1 = fmaf(xbv.y, w1.y, a1);                   \
    a2 = fmaf(xbv.z, w1.z, a2); a3 = fmaf(xbv.w, w1.w, a3);                   \
    a0 = fmaf(xc.x, w2.x, a0);  a1 = fmaf(xc.y, w2.y, a1);                    \
    a2 = fmaf(xc.z, w2.z, a2);  a3 = fmaf(xc.w, w2.w, a3);                    \
    a0 = fmaf(xd.x, w3.x, a0);  a1 = fmaf(xd.y, w3.y, a1);                    \
    a2 = fmaf(xd.z, w3.z, a2);  a3 = fmaf(xd.w, w3.w, a3);                    \
    uint4 qa = *(const uint4*)mp;                                             \
    uint4 qb = *(const uint4*)(mp + 4);                                       \
    for (int c = 0; c < ncw - 1; ++c) {                                       \
      const uint32_t* cpn = mp + (size_t)(c + 1) * (RES * 8);                 \
      const uint4 na = *(const uint4*)cpn;                                    \
      const uint4 nb = *(const uint4*)(cpn + 4);                              \
      G8(qa, qb, (PAR) * 4096)                                                \
      qa = na; qb = nb;                                                       \
    }                                                                         \
    G8(qa, qb, (PAR) * 4096)                                                  \
    const float acc = (a0 + a1) + (a2 + a3);                                  \
    const float e   = exp2f(acc * 2.885390081777927f);                        \
    const float th  = 1.0f - 2.0f * __builtin_amdgcn_rcpf(e + 1.0f);          \
    const float hn  = fmaf(0.7f, th, 0.3f * hreg);                            \
    hreg = hn;                                                                \
    smem[((PAR) ^ 1) * RES + tid] = hn;                                       \
    __syncthreads();                                                          \
  }

__global__ __launch_bounds__(1024) void esn_scan(
    const float* __restrict__ x, const float* __restrict__ state,
    const float* __restrict__ Win, const float* __restrict__ Woutw,
    const float* __restrict__ Woutb,
    const uint32_t* __restrict__ mat, const uint32_t* __restrict__ perm,
    const uint32_t* __restrict__ wnc,
    float* __restrict__ out) {
  __shared__ float smem[2 * RES + 32];   // h dbuf @0/@4096 bytes, x @ 8192

  const int b    = blockIdx.x;
  const int tid  = threadIdx.x;
  const int wave = tid >> 6;
  const int lane = tid & 63;
  const int row  = (int)perm[tid];
  const int ncw  = (int)__builtin_amdgcn_readfirstlane(wnc[wave]);

  const float4* winp = (const float4*)(Win + (size_t)row * INPD);
  const float4 w0 = winp[0], w1 = winp[1], w2 = winp[2], w3 = winp[3];

  float wo[16];
  const float* wor = Woutw + (size_t)wave * RES;
#pragma unroll
  for (int j = 0; j < 16; ++j)
    wo[j] = (wave < OUTD) ? wor[(int)perm[lane + 64 * j]] : 0.0f;
  const float bw = (wave < OUTD) ? Woutb[wave] : 0.0f;

  float hreg = state[(size_t)b * RES + row];
  smem[tid] = hreg;                      // sorted-space h, parity 0
  const float* xr = x + (size_t)b * SEQ * INPD;
  if (tid < 4) ((float4*)(smem + 2 * RES))[tid] = ((const float4*)xr)[tid];
  __syncthreads();

  const uint32_t* mp = mat + (size_t)tid * 8;
  float* finals = out + (size_t)BATCH * SEQ * OUTD;

  for (int t = 0; t < SEQ; t += 2) {
    STEP(0, t)
    STEP(1, t + 1)
  }

  // out[SEQ-1] from parity-0 buffer (= states[SEQ-1]); final state
  if (wave < OUTD) {
    float s = 0.0f;
#pragma unroll
    for (int j = 0; j < 16; ++j) s = fmaf(smem[lane + 64 * j], wo[j], s);
#pragma unroll
    for (int d = 1; d < 64; d <<= 1) s += __shfl_xor(s, d);
    if (lane == 0) out[((size_t)b * SEQ + (SEQ - 1)) * OUTD + wave] = s + bw;
  }
  finals[(size_t)b * RES + row] = hreg;
}

// ---------------------------------------------------------------------------
extern "C" void kernel_launch(void* const* d_in, const int* in_sizes, int n_in,
                              void* d_out, int out_size, void* d_ws, size_t ws_size,
                              hipStream_t stream) {
  const float* x     = (const float*)d_in[0];
  const float* state = (const float*)d_in[1];
  const float* Win   = (const float*)d_in[2];
  const float* Wres  = (const float*)d_in[3];
  const float* Woutw = (const float*)d_in[4];
  const float* Woutb = (const float*)d_in[5];
  float* out = (float*)d_out;

  uint8_t*  ws   = (uint8_t*)d_ws;
  uint32_t* mat  = (uint32_t*)ws;
  uint32_t* eff  = (uint32_t*)(ws + MAT_BYTES);
  uint32_t* perm = (uint32_t*)(ws + MAT_BYTES + 4096);
  uint32_t* wnc  = (uint32_t*)(ws + MAT_BYTES + 8192);
  uint32_t* invp = (uint32_t*)(ws + MAT_BYTES + 12288);

  esn_count<<<RES, 32, 0, stream>>>(Wres, eff);
  esn_sort<<<1, RES, 0, stream>>>(eff, perm, invp);
  esn_sched<<<16, 64, 0, stream>>>(Wres, perm, invp, mat, wnc);
  esn_scan<<<BATCH, RES, 0, stream>>>(x, state, Win, Woutw, Woutb,
                                      mat, perm, wnc, out);
}